// Round 1
// baseline (750.188 us; speedup 1.0000x reference)
//
#include <hip/hip_runtime.h>
#include <cstdint>
#include <cstddef>

#define N_NODES 8192
#define N_EDGES 131072
#define F_IN    512
#define H1C     32
#define H2C     16

// ---------------- helpers ----------------

__device__ __forceinline__ float block_reduce_sum_256(float v) {
    #pragma unroll
    for (int off = 32; off; off >>= 1) v += __shfl_down(v, off, 64);
    __shared__ float sred[4];
    int lane = threadIdx.x & 63, wid = threadIdx.x >> 6;
    if (lane == 0) sred[wid] = v;
    __syncthreads();
    return (threadIdx.x == 0) ? (sred[0] + sred[1] + sred[2] + sred[3]) : 0.0f;
}

__device__ __forceinline__ float bce_elem(float l, int y) {
    // y=1: 10*softplus(-l); y=0: softplus(l).  lse = log(1+exp(-|l|))
    float lse = __logf(1.0f + __expf(-fabsf(l)));
    return y ? 10.0f * (lse + fmaxf(-l, 0.0f)) : (lse + fmaxf(l, 0.0f));
}

// ---------------- kernels ----------------

__global__ void k_deg(const int* __restrict__ dst, int* __restrict__ deg) {
    int e = blockIdx.x * 256 + threadIdx.x;
    if (e < N_EDGES) atomicAdd(&deg[dst[e]], 1);
}

__global__ void k_dinv(const int* __restrict__ deg, float* __restrict__ dinv) {
    int i = blockIdx.x * 256 + threadIdx.x;
    dinv[i] = rsqrtf((float)deg[i] + 1.0f);
}

// h = x @ W1 : [8192,512] x [512,32], 128-row tiles
__global__ void k_gemm1(const float* __restrict__ x, const float* __restrict__ W1,
                        float* __restrict__ h) {
    __shared__ float xs[128][33];   // padded: bank = (tr + k) % 32, conflict-free
    __shared__ float wsm[32][32];
    int tid = threadIdx.x;
    int tc = tid & 7;        // col group: cols tc*4 .. tc*4+3
    int tr = tid >> 3;       // 0..31, rows tr + 32*i
    int rowbase = blockIdx.x * 128;

    float accx[4], accy[4], accz[4], accw[4];
    #pragma unroll
    for (int i = 0; i < 4; ++i) { accx[i]=0.f; accy[i]=0.f; accz[i]=0.f; accw[i]=0.f; }

    for (int kc = 0; kc < F_IN / 32; ++kc) {
        __syncthreads();
        // stage x tile: 128 rows x 32 k  (1024 float4)
        #pragma unroll
        for (int it = 0; it < 4; ++it) {
            int f = tid + it * 256;
            int r = f >> 3, pos = (f & 7) << 2;
            float4 v = *(const float4*)&x[(size_t)(rowbase + r) * F_IN + kc * 32 + pos];
            xs[r][pos + 0] = v.x; xs[r][pos + 1] = v.y;
            xs[r][pos + 2] = v.z; xs[r][pos + 3] = v.w;
        }
        // stage W1 tile: 32 k x 32 cols (256 float4)
        {
            int k = tid >> 3, pos = (tid & 7) << 2;
            *(float4*)&wsm[k][pos] = *(const float4*)&W1[(size_t)(kc * 32 + k) * H1C + pos];
        }
        __syncthreads();
        #pragma unroll
        for (int k = 0; k < 32; ++k) {
            float4 wv = *(const float4*)&wsm[k][tc << 2];
            float x0 = xs[tr][k], x1 = xs[tr + 32][k], x2 = xs[tr + 64][k], x3 = xs[tr + 96][k];
            accx[0] += x0 * wv.x; accy[0] += x0 * wv.y; accz[0] += x0 * wv.z; accw[0] += x0 * wv.w;
            accx[1] += x1 * wv.x; accy[1] += x1 * wv.y; accz[1] += x1 * wv.z; accw[1] += x1 * wv.w;
            accx[2] += x2 * wv.x; accy[2] += x2 * wv.y; accz[2] += x2 * wv.z; accw[2] += x2 * wv.w;
            accx[3] += x3 * wv.x; accy[3] += x3 * wv.y; accz[3] += x3 * wv.z; accw[3] += x3 * wv.w;
        }
    }
    #pragma unroll
    for (int i = 0; i < 4; ++i) {
        float4 v; v.x = accx[i]; v.y = accy[i]; v.z = accz[i]; v.w = accw[i];
        *(float4*)&h[(size_t)(rowbase + tr + 32 * i) * H1C + (tc << 2)] = v;
    }
}

// scatter layer1: agg1[dst] += h[src] * dinv[src]*dinv[dst]   (32 lanes per edge)
__global__ void k_scatter1(const int* __restrict__ src, const int* __restrict__ dst,
                           const float* __restrict__ h, const float* __restrict__ dinv,
                           float* __restrict__ agg1) {
    int gid = blockIdx.x * 256 + threadIdx.x;
    int e = gid >> 5, f = gid & 31;
    int s = src[e], d = dst[e];
    float c = dinv[s] * dinv[d];
    unsafeAtomicAdd(&agg1[(d << 5) + f], h[(s << 5) + f] * c);
}

// h1 = relu(agg1 + h * dinv^2)
__global__ void k_h1(const float* __restrict__ agg1, const float* __restrict__ h,
                     const float* __restrict__ dinv, float* __restrict__ h1) {
    int i4 = blockIdx.x * 256 + threadIdx.x;   // over N*H1/4 = 65536
    int row = i4 >> 3;
    float di = dinv[row], d2 = di * di;
    float4 a = ((const float4*)agg1)[i4];
    float4 hv = ((const float4*)h)[i4];
    float4 r;
    r.x = fmaxf(a.x + hv.x * d2, 0.0f);
    r.y = fmaxf(a.y + hv.y * d2, 0.0f);
    r.z = fmaxf(a.z + hv.z * d2, 0.0f);
    r.w = fmaxf(a.w + hv.w * d2, 0.0f);
    ((float4*)h1)[i4] = r;
}

// h2mu = h1@W2, h2lv = h1@W3 (one thread per output element, both mats)
__global__ void k_gemm2(const float* __restrict__ h1, const float* __restrict__ W2,
                        const float* __restrict__ W3, float* __restrict__ h2mu,
                        float* __restrict__ h2lv) {
    __shared__ float w2s[H1C * H2C], w3s[H1C * H2C];
    int tid = threadIdx.x;
    for (int i = tid; i < H1C * H2C; i += 256) { w2s[i] = W2[i]; w3s[i] = W3[i]; }
    __syncthreads();
    int gid = blockIdx.x * 256 + tid;
    int row = gid >> 5, c = gid & 31, col = c & 15;
    const float* wsrc = (c & 16) ? w3s : w2s;
    const float* hr = &h1[(size_t)row << 5];
    float acc = 0.0f;
    #pragma unroll
    for (int k = 0; k < H1C; ++k) acc += hr[k] * wsrc[(k << 4) + col];
    if (c & 16) h2lv[(row << 4) + col] = acc;
    else        h2mu[(row << 4) + col] = acc;
}

// scatter layer2: both mu and logvar (16 lanes each per edge)
__global__ void k_scatter2(const int* __restrict__ src, const int* __restrict__ dst,
                           const float* __restrict__ h2mu, const float* __restrict__ h2lv,
                           const float* __restrict__ dinv, float* __restrict__ aggmu,
                           float* __restrict__ agglv) {
    int gid = blockIdx.x * 256 + threadIdx.x;
    int e = gid >> 5, f = gid & 31;
    int s = src[e], d = dst[e];
    float c = dinv[s] * dinv[d];
    int ff = f & 15;
    if (f < 16) unsafeAtomicAdd(&aggmu[(d << 4) + ff], h2mu[(s << 4) + ff] * c);
    else        unsafeAtomicAdd(&agglv[(d << 4) + ff], h2lv[(s << 4) + ff] * c);
}

// mu/logvar finalize, z = eps*exp(lv)+mu, kld partials, write mu to out
__global__ void k_zmu(const float* __restrict__ aggmu, const float* __restrict__ agglv,
                      const float* __restrict__ h2mu, const float* __restrict__ h2lv,
                      const float* __restrict__ dinv, const float* __restrict__ eps,
                      float* __restrict__ zbuf, float* __restrict__ out,
                      float* __restrict__ kldp) {
    int gid = blockIdx.x * 256 + threadIdx.x;   // over N*H2 = 131072
    int row = gid >> 4;
    float di = dinv[row], d2 = di * di;
    float m  = aggmu[gid] + h2mu[gid] * d2;
    float lv = agglv[gid] + h2lv[gid] * d2;
    float el = __expf(lv);
    float zv = eps[gid] * el + m;
    zbuf[gid] = zv;
    out[1 + gid] = m;
    float kt = 1.0f + 2.0f * lv - m * m - el * el;
    float bs = block_reduce_sum_256(kt);
    if (threadIdx.x == 0) kldp[blockIdx.x] = bs;
}

// BCE over 64x64 logits tile: logits = z_tile_r . z_tile_c^T, reduce softplus terms
__global__ void k_bce(const float* __restrict__ z, const int* __restrict__ adj,
                      float* __restrict__ part) {
    __shared__ float zrT[16][64];
    __shared__ float zcT[16][64];
    int tid = threadIdx.x;
    int rbase = blockIdx.y << 6, cbase = blockIdx.x << 6;
    {
        int r = tid >> 2, kc = (tid & 3) << 2;
        float4 v = *(const float4*)&z[(size_t)(rbase + r) * H2C + kc];
        zrT[kc + 0][r] = v.x; zrT[kc + 1][r] = v.y; zrT[kc + 2][r] = v.z; zrT[kc + 3][r] = v.w;
        float4 w = *(const float4*)&z[(size_t)(cbase + r) * H2C + kc];
        zcT[kc + 0][r] = w.x; zcT[kc + 1][r] = w.y; zcT[kc + 2][r] = w.z; zcT[kc + 3][r] = w.w;
    }
    __syncthreads();
    int tx = tid & 15, ty = tid >> 4;
    float a0x=0,a0y=0,a0z=0,a0w=0, a1x=0,a1y=0,a1z=0,a1w=0;
    float a2x=0,a2y=0,a2z=0,a2w=0, a3x=0,a3y=0,a3z=0,a3w=0;
    #pragma unroll
    for (int k = 0; k < H2C; ++k) {
        float4 av = *(const float4*)&zrT[k][ty << 2];
        float4 ac = *(const float4*)&zcT[k][tx << 2];
        a0x += av.x * ac.x; a0y += av.x * ac.y; a0z += av.x * ac.z; a0w += av.x * ac.w;
        a1x += av.y * ac.x; a1y += av.y * ac.y; a1z += av.y * ac.z; a1w += av.y * ac.w;
        a2x += av.z * ac.x; a2y += av.z * ac.y; a2z += av.z * ac.z; a2w += av.z * ac.w;
        a3x += av.w * ac.x; a3y += av.w * ac.y; a3z += av.w * ac.z; a3w += av.w * ac.w;
    }
    float lsum = 0.0f;
    {
        const int4* r0 = (const int4*)&adj[(size_t)(rbase + (ty << 2) + 0) * N_NODES + cbase + (tx << 2)];
        const int4* r1 = (const int4*)&adj[(size_t)(rbase + (ty << 2) + 1) * N_NODES + cbase + (tx << 2)];
        const int4* r2 = (const int4*)&adj[(size_t)(rbase + (ty << 2) + 2) * N_NODES + cbase + (tx << 2)];
        const int4* r3 = (const int4*)&adj[(size_t)(rbase + (ty << 2) + 3) * N_NODES + cbase + (tx << 2)];
        int4 y0 = *r0, y1 = *r1, y2 = *r2, y3 = *r3;
        lsum += bce_elem(a0x, y0.x) + bce_elem(a0y, y0.y) + bce_elem(a0z, y0.z) + bce_elem(a0w, y0.w);
        lsum += bce_elem(a1x, y1.x) + bce_elem(a1y, y1.y) + bce_elem(a1z, y1.z) + bce_elem(a1w, y1.w);
        lsum += bce_elem(a2x, y2.x) + bce_elem(a2y, y2.y) + bce_elem(a2z, y2.z) + bce_elem(a2w, y2.w);
        lsum += bce_elem(a3x, y3.x) + bce_elem(a3y, y3.y) + bce_elem(a3z, y3.z) + bce_elem(a3w, y3.w);
    }
    float bs = block_reduce_sum_256(lsum);
    if (tid == 0) part[blockIdx.y * gridDim.x + blockIdx.x] = bs;
}

__global__ void k_final(const float* __restrict__ part, const float* __restrict__ kldp,
                        const float* __restrict__ norm, float* __restrict__ out) {
    double s = 0.0, k = 0.0;
    for (int i = threadIdx.x; i < 16384; i += 256) s += (double)part[i];
    for (int i = threadIdx.x; i < 512; i += 256) k += (double)kldp[i];
    #pragma unroll
    for (int off = 32; off; off >>= 1) {
        s += __shfl_down(s, off, 64);
        k += __shfl_down(k, off, 64);
    }
    __shared__ double ss[4], kk[4];
    int lane = threadIdx.x & 63, wid = threadIdx.x >> 6;
    if (lane == 0) { ss[wid] = s; kk[wid] = k; }
    __syncthreads();
    if (threadIdx.x == 0) {
        double st = ss[0] + ss[1] + ss[2] + ss[3];
        double kt = kk[0] + kk[1] + kk[2] + kk[3];
        double bce = st / ((double)N_NODES * (double)N_NODES);
        double kld = (-0.5 / (double)N_NODES) * (kt / (double)N_NODES);
        out[0] = (float)((double)norm[0] * bce + kld);
    }
}

// ---------------- launch ----------------

extern "C" void kernel_launch(void* const* d_in, const int* in_sizes, int n_in,
                              void* d_out, int out_size, void* d_ws, size_t ws_size,
                              hipStream_t stream) {
    const float* x    = (const float*)d_in[0];
    const int*   ei   = (const int*)d_in[1];
    const int*   adj  = (const int*)d_in[2];
    const float* eps  = (const float*)d_in[3];
    const float* norm = (const float*)d_in[4];
    const float* W1   = (const float*)d_in[5];
    const float* W2   = (const float*)d_in[6];
    const float* W3   = (const float*)d_in[7];
    float* out = (float*)d_out;
    char*  ws  = (char*)d_ws;

    const int* src = ei;
    const int* dst = ei + N_EDGES;

    int*   deg    = (int*)  (ws + 0);
    float* dinv   = (float*)(ws + 32768);
    float* h      = (float*)(ws + 65536);
    float* agg1   = (float*)(ws + 1114112);
    float* h1     = (float*)(ws + 2162688);
    float* h2mu   = (float*)(ws + 3211264);
    float* h2lv   = (float*)(ws + 3735552);
    float* aggmu  = (float*)(ws + 4259840);
    float* agglv  = (float*)(ws + 4784128);
    float* zbuf   = (float*)(ws + 5308416);
    float* part   = (float*)(ws + 5832704);   // 16384 f32
    float* kldp   = (float*)(ws + 5898240);   // 512 f32

    hipMemsetAsync(deg, 0, 32768, stream);
    hipMemsetAsync(agg1, 0, 1048576, stream);
    hipMemsetAsync(aggmu, 0, 1048576, stream);  // covers agglv too

    k_deg<<<N_EDGES / 256, 256, 0, stream>>>(dst, deg);
    k_dinv<<<N_NODES / 256, 256, 0, stream>>>(deg, dinv);
    k_gemm1<<<N_NODES / 128, 256, 0, stream>>>(x, W1, h);
    k_scatter1<<<(N_EDGES * 32) / 256, 256, 0, stream>>>(src, dst, h, dinv, agg1);
    k_h1<<<(N_NODES * H1C / 4) / 256, 256, 0, stream>>>(agg1, h, dinv, h1);
    k_gemm2<<<(N_NODES * 32) / 256, 256, 0, stream>>>(h1, W2, W3, h2mu, h2lv);
    k_scatter2<<<(N_EDGES * 32) / 256, 256, 0, stream>>>(src, dst, h2mu, h2lv, dinv, aggmu, agglv);
    k_zmu<<<(N_NODES * H2C) / 256, 256, 0, stream>>>(aggmu, agglv, h2mu, h2lv, dinv, eps, zbuf, out, kldp);
    k_bce<<<dim3(128, 128), 256, 0, stream>>>(zbuf, adj, part);
    k_final<<<1, 256, 0, stream>>>(part, kldp, norm, out);
}

// Round 2
// 634.837 us; speedup vs baseline: 1.1817x; 1.1817x over previous
//
#include <hip/hip_runtime.h>
#include <cstdint>
#include <cstddef>

#define N_NODES 8192
#define N_EDGES 131072
#define F_IN    512
#define H1C     32
#define H2C     16

typedef int           i32x4 __attribute__((ext_vector_type(4)));
typedef unsigned char u8x4  __attribute__((ext_vector_type(4)));

// ---------------- helpers ----------------

__device__ __forceinline__ float block_reduce_sum_256(float v) {
    #pragma unroll
    for (int off = 32; off; off >>= 1) v += __shfl_down(v, off, 64);
    __shared__ float sred[4];
    int lane = threadIdx.x & 63, wid = threadIdx.x >> 6;
    if (lane == 0) sred[wid] = v;
    __syncthreads();
    return (threadIdx.x == 0) ? (sred[0] + sred[1] + sred[2] + sred[3]) : 0.0f;
}

__device__ __forceinline__ float bce_elem(float l, int y) {
    // y=1: 10*softplus(-l); y=0: softplus(l).  lse = log(1+exp(-|l|))
    float lse = __logf(1.0f + __expf(-fabsf(l)));
    return y ? 10.0f * (lse + fmaxf(-l, 0.0f)) : (lse + fmaxf(l, 0.0f));
}

// ---------------- kernels ----------------

__global__ void k_deg(const int* __restrict__ dst, int* __restrict__ deg) {
    int e = blockIdx.x * 256 + threadIdx.x;
    if (e < N_EDGES) atomicAdd(&deg[dst[e]], 1);
}

__global__ void k_dinv(const int* __restrict__ deg, float* __restrict__ dinv) {
    int i = blockIdx.x * 256 + threadIdx.x;
    dinv[i] = rsqrtf((float)deg[i] + 1.0f);
}

// adj int32 -> uint8, pure stream. nt loads: dead data, don't pollute caches.
// Normal stores: the 67MB byte buffer should land in L3 for k_bce to re-read.
__global__ void k_pack(const int* __restrict__ adj, unsigned char* __restrict__ out) {
    size_t i = (size_t)blockIdx.x * 256 + threadIdx.x;
    i32x4 v = __builtin_nontemporal_load((const i32x4*)adj + i);
    u8x4 b;
    b.x = (unsigned char)v.x; b.y = (unsigned char)v.y;
    b.z = (unsigned char)v.z; b.w = (unsigned char)v.w;
    *((u8x4*)out + i) = b;
}

// h = x @ W1 : [8192,512] x [512,32], 128-row tiles
__global__ void k_gemm1(const float* __restrict__ x, const float* __restrict__ W1,
                        float* __restrict__ h) {
    __shared__ float xs[128][33];
    __shared__ float wsm[32][32];
    int tid = threadIdx.x;
    int tc = tid & 7;
    int tr = tid >> 3;
    int rowbase = blockIdx.x * 128;

    float accx[4], accy[4], accz[4], accw[4];
    #pragma unroll
    for (int i = 0; i < 4; ++i) { accx[i]=0.f; accy[i]=0.f; accz[i]=0.f; accw[i]=0.f; }

    for (int kc = 0; kc < F_IN / 32; ++kc) {
        __syncthreads();
        #pragma unroll
        for (int it = 0; it < 4; ++it) {
            int f = tid + it * 256;
            int r = f >> 3, pos = (f & 7) << 2;
            float4 v = *(const float4*)&x[(size_t)(rowbase + r) * F_IN + kc * 32 + pos];
            xs[r][pos + 0] = v.x; xs[r][pos + 1] = v.y;
            xs[r][pos + 2] = v.z; xs[r][pos + 3] = v.w;
        }
        {
            int k = tid >> 3, pos = (tid & 7) << 2;
            *(float4*)&wsm[k][pos] = *(const float4*)&W1[(size_t)(kc * 32 + k) * H1C + pos];
        }
        __syncthreads();
        #pragma unroll
        for (int k = 0; k < 32; ++k) {
            float4 wv = *(const float4*)&wsm[k][tc << 2];
            float x0 = xs[tr][k], x1 = xs[tr + 32][k], x2 = xs[tr + 64][k], x3 = xs[tr + 96][k];
            accx[0] += x0 * wv.x; accy[0] += x0 * wv.y; accz[0] += x0 * wv.z; accw[0] += x0 * wv.w;
            accx[1] += x1 * wv.x; accy[1] += x1 * wv.y; accz[1] += x1 * wv.z; accw[1] += x1 * wv.w;
            accx[2] += x2 * wv.x; accy[2] += x2 * wv.y; accz[2] += x2 * wv.z; accw[2] += x2 * wv.w;
            accx[3] += x3 * wv.x; accy[3] += x3 * wv.y; accz[3] += x3 * wv.z; accw[3] += x3 * wv.w;
        }
    }
    #pragma unroll
    for (int i = 0; i < 4; ++i) {
        float4 v; v.x = accx[i]; v.y = accy[i]; v.z = accz[i]; v.w = accw[i];
        *(float4*)&h[(size_t)(rowbase + tr + 32 * i) * H1C + (tc << 2)] = v;
    }
}

__global__ void k_scatter1(const int* __restrict__ src, const int* __restrict__ dst,
                           const float* __restrict__ h, const float* __restrict__ dinv,
                           float* __restrict__ agg1) {
    int gid = blockIdx.x * 256 + threadIdx.x;
    int e = gid >> 5, f = gid & 31;
    int s = src[e], d = dst[e];
    float c = dinv[s] * dinv[d];
    unsafeAtomicAdd(&agg1[(d << 5) + f], h[(s << 5) + f] * c);
}

__global__ void k_h1(const float* __restrict__ agg1, const float* __restrict__ h,
                     const float* __restrict__ dinv, float* __restrict__ h1) {
    int i4 = blockIdx.x * 256 + threadIdx.x;
    int row = i4 >> 3;
    float di = dinv[row], d2 = di * di;
    float4 a = ((const float4*)agg1)[i4];
    float4 hv = ((const float4*)h)[i4];
    float4 r;
    r.x = fmaxf(a.x + hv.x * d2, 0.0f);
    r.y = fmaxf(a.y + hv.y * d2, 0.0f);
    r.z = fmaxf(a.z + hv.z * d2, 0.0f);
    r.w = fmaxf(a.w + hv.w * d2, 0.0f);
    ((float4*)h1)[i4] = r;
}

__global__ void k_gemm2(const float* __restrict__ h1, const float* __restrict__ W2,
                        const float* __restrict__ W3, float* __restrict__ h2mu,
                        float* __restrict__ h2lv) {
    __shared__ float w2s[H1C * H2C], w3s[H1C * H2C];
    int tid = threadIdx.x;
    for (int i = tid; i < H1C * H2C; i += 256) { w2s[i] = W2[i]; w3s[i] = W3[i]; }
    __syncthreads();
    int gid = blockIdx.x * 256 + tid;
    int row = gid >> 5, c = gid & 31, col = c & 15;
    const float* wsrc = (c & 16) ? w3s : w2s;
    const float* hr = &h1[(size_t)row << 5];
    float acc = 0.0f;
    #pragma unroll
    for (int k = 0; k < H1C; ++k) acc += hr[k] * wsrc[(k << 4) + col];
    if (c & 16) h2lv[(row << 4) + col] = acc;
    else        h2mu[(row << 4) + col] = acc;
}

__global__ void k_scatter2(const int* __restrict__ src, const int* __restrict__ dst,
                           const float* __restrict__ h2mu, const float* __restrict__ h2lv,
                           const float* __restrict__ dinv, float* __restrict__ aggmu,
                           float* __restrict__ agglv) {
    int gid = blockIdx.x * 256 + threadIdx.x;
    int e = gid >> 5, f = gid & 31;
    int s = src[e], d = dst[e];
    float c = dinv[s] * dinv[d];
    int ff = f & 15;
    if (f < 16) unsafeAtomicAdd(&aggmu[(d << 4) + ff], h2mu[(s << 4) + ff] * c);
    else        unsafeAtomicAdd(&agglv[(d << 4) + ff], h2lv[(s << 4) + ff] * c);
}

__global__ void k_zmu(const float* __restrict__ aggmu, const float* __restrict__ agglv,
                      const float* __restrict__ h2mu, const float* __restrict__ h2lv,
                      const float* __restrict__ dinv, const float* __restrict__ eps,
                      float* __restrict__ zbuf, float* __restrict__ out,
                      float* __restrict__ kldp) {
    int gid = blockIdx.x * 256 + threadIdx.x;
    int row = gid >> 4;
    float di = dinv[row], d2 = di * di;
    float m  = aggmu[gid] + h2mu[gid] * d2;
    float lv = agglv[gid] + h2lv[gid] * d2;
    float el = __expf(lv);
    float zv = eps[gid] * el + m;
    zbuf[gid] = zv;
    out[1 + gid] = m;
    float kt = 1.0f + 2.0f * lv - m * m - el * el;
    float bs = block_reduce_sum_256(kt);
    if (threadIdx.x == 0) kldp[blockIdx.x] = bs;
}

// BCE over 64x64 logits tile. PACKED: adj as uint8 (1/4 the stream).
// adj loads issued before the FMA loop so the miss latency hides under compute.
template<bool PACKED>
__global__ void k_bce(const float* __restrict__ z, const void* __restrict__ adjv,
                      float* __restrict__ part) {
    __shared__ float zrT[16][68];   // pad 68: staging write conflict 4-way -> 2-way (free)
    __shared__ float zcT[16][68];
    int tid = threadIdx.x;
    int rbase = blockIdx.y << 6, cbase = blockIdx.x << 6;
    {
        int r = tid >> 2, kc = (tid & 3) << 2;
        float4 v = *(const float4*)&z[(size_t)(rbase + r) * H2C + kc];
        zrT[kc + 0][r] = v.x; zrT[kc + 1][r] = v.y; zrT[kc + 2][r] = v.z; zrT[kc + 3][r] = v.w;
        float4 w = *(const float4*)&z[(size_t)(cbase + r) * H2C + kc];
        zcT[kc + 0][r] = w.x; zcT[kc + 1][r] = w.y; zcT[kc + 2][r] = w.z; zcT[kc + 3][r] = w.w;
    }
    int tx = tid & 15, ty = tid >> 4;

    // issue adjacency loads early (independent of LDS) — latency hides under FMA loop
    int y[16];
    if (PACKED) {
        const unsigned char* a = (const unsigned char*)adjv;
        #pragma unroll
        for (int r = 0; r < 4; ++r) {
            u8x4 v = __builtin_nontemporal_load(
                (const u8x4*)&a[(size_t)(rbase + (ty << 2) + r) * N_NODES + cbase + (tx << 2)]);
            y[r * 4 + 0] = v.x; y[r * 4 + 1] = v.y; y[r * 4 + 2] = v.z; y[r * 4 + 3] = v.w;
        }
    } else {
        const int* a = (const int*)adjv;
        #pragma unroll
        for (int r = 0; r < 4; ++r) {
            i32x4 v = __builtin_nontemporal_load(
                (const i32x4*)&a[(size_t)(rbase + (ty << 2) + r) * N_NODES + cbase + (tx << 2)]);
            y[r * 4 + 0] = v.x; y[r * 4 + 1] = v.y; y[r * 4 + 2] = v.z; y[r * 4 + 3] = v.w;
        }
    }
    __syncthreads();

    float a0x=0,a0y=0,a0z=0,a0w=0, a1x=0,a1y=0,a1z=0,a1w=0;
    float a2x=0,a2y=0,a2z=0,a2w=0, a3x=0,a3y=0,a3z=0,a3w=0;
    #pragma unroll
    for (int k = 0; k < H2C; ++k) {
        float4 av = *(const float4*)&zrT[k][ty << 2];
        float4 ac = *(const float4*)&zcT[k][tx << 2];
        a0x += av.x * ac.x; a0y += av.x * ac.y; a0z += av.x * ac.z; a0w += av.x * ac.w;
        a1x += av.y * ac.x; a1y += av.y * ac.y; a1z += av.y * ac.z; a1w += av.y * ac.w;
        a2x += av.z * ac.x; a2y += av.z * ac.y; a2z += av.z * ac.z; a2w += av.z * ac.w;
        a3x += av.w * ac.x; a3y += av.w * ac.y; a3z += av.w * ac.z; a3w += av.w * ac.w;
    }
    float lsum = 0.0f;
    lsum += bce_elem(a0x, y[0])  + bce_elem(a0y, y[1])  + bce_elem(a0z, y[2])  + bce_elem(a0w, y[3]);
    lsum += bce_elem(a1x, y[4])  + bce_elem(a1y, y[5])  + bce_elem(a1z, y[6])  + bce_elem(a1w, y[7]);
    lsum += bce_elem(a2x, y[8])  + bce_elem(a2y, y[9])  + bce_elem(a2z, y[10]) + bce_elem(a2w, y[11]);
    lsum += bce_elem(a3x, y[12]) + bce_elem(a3y, y[13]) + bce_elem(a3z, y[14]) + bce_elem(a3w, y[15]);

    float bs = block_reduce_sum_256(lsum);
    if (tid == 0) part[blockIdx.y * gridDim.x + blockIdx.x] = bs;
}

__global__ void k_final(const float* __restrict__ part, const float* __restrict__ kldp,
                        const float* __restrict__ norm, float* __restrict__ out) {
    double s = 0.0, k = 0.0;
    for (int i = threadIdx.x; i < 16384; i += 256) s += (double)part[i];
    for (int i = threadIdx.x; i < 512; i += 256) k += (double)kldp[i];
    #pragma unroll
    for (int off = 32; off; off >>= 1) {
        s += __shfl_down(s, off, 64);
        k += __shfl_down(k, off, 64);
    }
    __shared__ double ss[4], kk[4];
    int lane = threadIdx.x & 63, wid = threadIdx.x >> 6;
    if (lane == 0) { ss[wid] = s; kk[wid] = k; }
    __syncthreads();
    if (threadIdx.x == 0) {
        double st = ss[0] + ss[1] + ss[2] + ss[3];
        double kt = kk[0] + kk[1] + kk[2] + kk[3];
        double bce = st / ((double)N_NODES * (double)N_NODES);
        double kld = (-0.5 / (double)N_NODES) * (kt / (double)N_NODES);
        out[0] = (float)((double)norm[0] * bce + kld);
    }
}

// ---------------- launch ----------------

extern "C" void kernel_launch(void* const* d_in, const int* in_sizes, int n_in,
                              void* d_out, int out_size, void* d_ws, size_t ws_size,
                              hipStream_t stream) {
    const float* x    = (const float*)d_in[0];
    const int*   ei   = (const int*)d_in[1];
    const int*   adj  = (const int*)d_in[2];
    const float* eps  = (const float*)d_in[3];
    const float* norm = (const float*)d_in[4];
    const float* W1   = (const float*)d_in[5];
    const float* W2   = (const float*)d_in[6];
    const float* W3   = (const float*)d_in[7];
    float* out = (float*)d_out;
    char*  ws  = (char*)d_ws;

    const int* src = ei;
    const int* dst = ei + N_EDGES;

    int*   deg    = (int*)  (ws + 0);
    float* dinv   = (float*)(ws + 32768);
    float* h      = (float*)(ws + 65536);
    float* agg1   = (float*)(ws + 1114112);
    float* h1     = (float*)(ws + 2162688);
    float* h2mu   = (float*)(ws + 3211264);
    float* h2lv   = (float*)(ws + 3735552);
    float* aggmu  = (float*)(ws + 4259840);
    float* agglv  = (float*)(ws + 4784128);
    float* zbuf   = (float*)(ws + 5308416);
    float* part   = (float*)(ws + 5832704);   // 16384 f32
    float* kldp   = (float*)(ws + 5898240);   // 512 f32
    unsigned char* adjb = (unsigned char*)(ws + 5900288);  // 64 MB packed adj

    const bool packed = ws_size >= (5900288ull + 67108864ull);

    if (packed) {
        // pure stream: 268 MB nt-read -> 67 MB write (cacheable, L3 target)
        k_pack<<<65536, 256, 0, stream>>>(adj, adjb);
    }

    hipMemsetAsync(deg, 0, 32768, stream);
    hipMemsetAsync(agg1, 0, 1048576, stream);
    hipMemsetAsync(aggmu, 0, 1048576, stream);  // covers agglv too

    k_deg<<<N_EDGES / 256, 256, 0, stream>>>(dst, deg);
    k_dinv<<<N_NODES / 256, 256, 0, stream>>>(deg, dinv);
    k_gemm1<<<N_NODES / 128, 256, 0, stream>>>(x, W1, h);
    k_scatter1<<<(N_EDGES * 32) / 256, 256, 0, stream>>>(src, dst, h, dinv, agg1);
    k_h1<<<(N_NODES * H1C / 4) / 256, 256, 0, stream>>>(agg1, h, dinv, h1);
    k_gemm2<<<(N_NODES * 32) / 256, 256, 0, stream>>>(h1, W2, W3, h2mu, h2lv);
    k_scatter2<<<(N_EDGES * 32) / 256, 256, 0, stream>>>(src, dst, h2mu, h2lv, dinv, aggmu, agglv);
    k_zmu<<<(N_NODES * H2C) / 256, 256, 0, stream>>>(aggmu, agglv, h2mu, h2lv, dinv, eps, zbuf, out, kldp);
    if (packed) k_bce<true><<<dim3(128, 128), 256, 0, stream>>>(zbuf, adjb, part);
    else        k_bce<false><<<dim3(128, 128), 256, 0, stream>>>(zbuf, adj, part);
    k_final<<<1, 256, 0, stream>>>(part, kldp, norm, out);
}